// Round 13
// baseline (92.374 us; speedup 1.0000x reference)
//
#include <hip/hip_runtime.h>
#include <stdint.h>

#define S_LEN 4096
#define HQ 32
#define HKV 8
#define DD 128
#define QBLK 128
#define KVROW (HKV * DD)

typedef __attribute__((ext_vector_type(8)))  __bf16 bf16x8;
typedef __attribute__((ext_vector_type(2)))  __bf16 bf16x2;
typedef __attribute__((ext_vector_type(4)))  float  f32x4;
typedef __attribute__((ext_vector_type(2)))  unsigned int u32x2;
typedef __attribute__((ext_vector_type(4)))  unsigned int u32x4;

// RNE f32x2 -> packed bf16x2 (compiler emits v_cvt_pk_bf16_f32).
__device__ __forceinline__ unsigned int pk2(float lo, float hi2) {
  bf16x2 t = {(__bf16)lo, (__bf16)hi2};
  return __builtin_bit_cast(unsigned int, t);
}
__device__ __forceinline__ bf16x8 mk8(unsigned int w0, unsigned int w1,
                                      unsigned int w2, unsigned int w3) {
  u32x4 u = {w0, w1, w2, w3};
  return __builtin_bit_cast(bf16x8, u);
}

// V swizzle, 64-byte XOR window (V rows are 320 B).
#define SWZV(d) ((((d) & 7) ^ (((d) >> 4) & 7)) << 3)

// Sliding-window split: each 512-thread block owns 32 q-rows (2 chunks x
// 4 heads = 8 units = 8 waves) and stages its 160-key window (80 KiB ->
// 2 blocks/CU). Staging is BRANCHLESS (clamped addresses) so the fully
// unrolled 20 global loads are hoistable into one in-flight batch --
// the r12 `if (tk>=0)` branch serialized them into ~4 HBM round-trips.
// Clamp safety: compute tiles are alive iff cg+tt>=8 iff all their global
// keys >= 0, so clamp-garbage K is never read and dead-tile V meets pf=0
// (finite garbage * 0 = 0).
__global__ __launch_bounds__(512, 4)
void swa_fwd(const float* __restrict__ Qg, const float* __restrict__ Kg,
             const float* __restrict__ Vg, float* __restrict__ Og) {
  __shared__ __align__(16) unsigned char Kl[40960];  // [c:160][d:128] bf16
  __shared__ __align__(16) unsigned char Vl[40960];  // V^T [d:128][c:160] bf16

  // XCD-aware bijective swizzle (nwg = 2048, divisible by 8).
  const int nwg  = gridDim.x;
  const int bid0 = blockIdx.x;
  const int bid  = (bid0 & 7) * (nwg >> 3) + (bid0 >> 3);

  const int j    = bid & 3;           // 32-row sub-block within the q-block
  const int n    = (bid >> 2) & 31;   // q-block index
  const int hkv  = (bid >> 7) & 7;
  const int b    = bid >> 10;
  const int tid  = threadIdx.x;
  const int lane = tid & 63;
  const int wv   = tid >> 6;          // 0..7
  const int g    = lane >> 4;         // 16-lane group 0..3
  const int l15  = lane & 15;

  // 8 units = 4 heads x 2 local 16-row q-chunks; one unit per wave.
  const int cc = wv & 1;              // local chunk 0..1
  const int h  = hkv * 4 + (wv >> 1);
  const int cg = 2 * j + cc;          // global chunk 0..7 (n==0 masking)
  const int qrow = n * QBLK + 32 * j + cc * 16 + l15;

  // ---- Q fragments FIRST: independent loads overlap the staging batch ----
  const float* qp = Qg + (size_t)(b * S_LEN + qrow) * (HQ * DD) + h * DD + g * 8;
  bf16x8 qf[4];
  #pragma unroll
  for (int dc = 0; dc < 4; ++dc) {
    f32x4 a  = *(const f32x4*)(qp + dc * 32);
    f32x4 c4 = *(const f32x4*)(qp + dc * 32 + 4);
    qf[dc] = mk8(pk2(a[0], a[1]), pk2(a[2], a[3]),
                 pk2(c4[0], c4[1]), pk2(c4[2], c4[3]));
  }

  // ---- stage the 160-key window: global keys kbase .. kbase+159 ----
  const int kbase = (n - 1) * QBLK + 32 * j;
  #pragma unroll
  for (int i = 0; i < 10; ++i) {
    const int e  = i * 512 + tid;     // 5120 float4-chunks = 160 rows x 32
    const int c  = e >> 5;            // window key index 0..159
    const int dc = e & 31;            // float4 index within d
    int tk = kbase + c;
    tk = tk > 0 ? tk : 0;             // branchless clamp (n==0 left pad)
    const size_t base = (size_t)(b * S_LEN + tk) * KVROW + hkv * DD + dc * 4;
    const f32x4 xk = *(const f32x4*)(Kg + base);
    const f32x4 xv = *(const f32x4*)(Vg + base);
    u32x2 kw = { pk2(xk[0], xk[1]), pk2(xk[2], xk[3]) };
    *(u32x2*)(&Kl[c * 256 + ((dc * 8) ^ ((c & 15) << 4))]) = kw;
    #pragma unroll
    for (int j4 = 0; j4 < 4; ++j4) {  // transposed scatter for V
      const int d = dc * 4 + j4;
      *(unsigned short*)(&Vl[d * 320 + ((c * 2) ^ SWZV(d))]) =
          __builtin_bit_cast(unsigned short, (__bf16)xv[j4]);
    }
  }
  __syncthreads();

  const float SC = 0.08838834764831845f * 1.44269504088896340f; // 1/sqrt(128)*log2e

  // O^T accumulators: o[dt] covers d = dt*16 + g*4 + r, q = l15.
  f32x4 o[8];
  #pragma unroll
  for (int dt = 0; dt < 8; ++dt) o[dt] = (f32x4){0.f, 0.f, 0.f, 0.f};
  float ls = 0.f;

  // 9 16-key tiles (local tiles cc..cc+8 in the 10-tile buffer), in pairs.
  #pragma unroll
  for (int pp = 0; pp < 5; ++pp) {
    const int tt0 = 2 * pp, tt1 = 2 * pp + 1;
    // n==0: window tiles with cg+tt < 8 are fully masked (left pad).
    if (n == 0 && cg + tt1 < 8) continue;   // both tiles dead

    unsigned int w0 = 0, w1 = 0, w2 = 0, w3 = 0;

    // ---- tile tt0: S^T = K_tile * Q^T (4 MFMAs over d) ----
    if (!(n == 0 && cg + tt0 < 8)) {
      const int c = (cc + tt0) * 16 + l15;   // key row (A: row=l15)
      f32x4 acc = {0.f, 0.f, 0.f, 0.f};
      __builtin_amdgcn_s_setprio(1);
      #pragma unroll
      for (int dc = 0; dc < 4; ++dc) {
        const bf16x8 kf = *(const bf16x8*)(
            &Kl[c * 256 + ((dc * 64 + g * 16) ^ ((c & 15) << 4))]);
        acc = __builtin_amdgcn_mfma_f32_16x16x32_bf16(kf, qf[dc], acc, 0, 0, 0);
      }
      __builtin_amdgcn_s_setprio(0);
      // mask: tt0==0: g4r>l15 ; tt0==8: g4r<=l15 ; else all valid.
      float p[4];
      #pragma unroll
      for (int r = 0; r < 4; ++r) {
        const int g4r = g * 4 + r;
        const float e = __builtin_amdgcn_exp2f(acc[r] * SC);
        bool valid = true;
        if (pp == 0) valid = (g4r > l15);
        if (pp == 4) valid = (g4r <= l15);
        p[r] = valid ? e : 0.f;
        ls += p[r];
      }
      w0 = pk2(p[0], p[1]);
      w1 = pk2(p[2], p[3]);
    }

    // ---- tile tt1 (pp<4 only; interior tiles never need a mask) ----
    if (pp < 4 && !(n == 0 && cg + tt1 < 8)) {
      const int c = (cc + tt1) * 16 + l15;
      f32x4 acc = {0.f, 0.f, 0.f, 0.f};
      __builtin_amdgcn_s_setprio(1);
      #pragma unroll
      for (int dc = 0; dc < 4; ++dc) {
        const bf16x8 kf = *(const bf16x8*)(
            &Kl[c * 256 + ((dc * 64 + g * 16) ^ ((c & 15) << 4))]);
        acc = __builtin_amdgcn_mfma_f32_16x16x32_bf16(kf, qf[dc], acc, 0, 0, 0);
      }
      __builtin_amdgcn_s_setprio(0);
      float p0 = __builtin_amdgcn_exp2f(acc[0] * SC);
      float p1 = __builtin_amdgcn_exp2f(acc[1] * SC);
      float p2 = __builtin_amdgcn_exp2f(acc[2] * SC);
      float p3 = __builtin_amdgcn_exp2f(acc[3] * SC);
      ls += p0 + p1 + p2 + p3;
      w2 = pk2(p0, p1);
      w3 = pk2(p2, p3);
    }

    // ---- PV with co-permuted key order: B = P^T in-register already;
    //      A (V^T) reads keys {tt0: g*4..+3, tt1: g*4..+3} to match. ----
    const bf16x8 pf = mk8(w0, w1, w2, w3);
    const int ck0 = ((cc + tt0) * 16 + g * 4) * 2;              // byte col
    const int ck1 = (pp < 4) ? ((cc + tt1) * 16 + g * 4) * 2 : ck0;
    __builtin_amdgcn_s_setprio(1);
    #pragma unroll
    for (int dt = 0; dt < 8; ++dt) {
      const int d  = dt * 16 + l15;       // A row = l15 within d-tile
      const int rb = d * 320;
      const int sz = SWZV(d);
      const u32x2 a0 = *(const u32x2*)(&Vl[rb + (ck0 ^ sz)]);
      const u32x2 a1 = *(const u32x2*)(&Vl[rb + (ck1 ^ sz)]);
      const bf16x8 vf = mk8(a0[0], a0[1], a1[0], a1[1]);
      o[dt] = __builtin_amdgcn_mfma_f32_16x16x32_bf16(vf, pf, o[dt], 0, 0, 0);
    }
    __builtin_amdgcn_s_setprio(0);
  }

  // ---- softmax denominator: all outputs of this lane share q = l15 ----
  ls += __shfl_xor(ls, 16);
  ls += __shfl_xor(ls, 32);
  const float inv = 1.0f / ls;

  float* op = Og + (size_t)(b * S_LEN + qrow) * (HQ * DD) + h * DD + g * 4;
  #pragma unroll
  for (int dt = 0; dt < 8; ++dt) {
    f32x4 v = o[dt];
    v[0] *= inv; v[1] *= inv; v[2] *= inv; v[3] *= inv;
    *(f32x4*)(op + dt * 16) = v;
  }
}

extern "C" void kernel_launch(void* const* d_in, const int* in_sizes, int n_in,
                              void* d_out, int out_size, void* d_ws, size_t ws_size,
                              hipStream_t stream) {
  const float* Q = (const float*)d_in[0];
  const float* K = (const float*)d_in[1];
  const float* V = (const float*)d_in[2];
  float* O = (float*)d_out;
  const int B = in_sizes[0] / (S_LEN * HQ * DD);
  const int nblocks = B * HKV * (S_LEN / QBLK) * 4;   // b, hkv, n, j (j fastest)
  swa_fwd<<<dim3(nblocks), dim3(512), 0, stream>>>(Q, K, V, O);
}

// Round 14
// 87.230 us; speedup vs baseline: 1.0590x; 1.0590x over previous
//
#include <hip/hip_runtime.h>
#include <stdint.h>

#define S_LEN 4096
#define HQ 32
#define HKV 8
#define DD 128
#define QBLK 128
#define KVROW (HKV * DD)

typedef __attribute__((ext_vector_type(8)))  __bf16 bf16x8;
typedef __attribute__((ext_vector_type(2)))  __bf16 bf16x2;
typedef __attribute__((ext_vector_type(4)))  float  f32x4;
typedef __attribute__((ext_vector_type(2)))  unsigned int u32x2;
typedef __attribute__((ext_vector_type(4)))  unsigned int u32x4;

// RNE f32x2 -> packed bf16x2 (compiler emits v_cvt_pk_bf16_f32).
__device__ __forceinline__ unsigned int pk2(float lo, float hi2) {
  bf16x2 t = {(__bf16)lo, (__bf16)hi2};
  return __builtin_bit_cast(unsigned int, t);
}
__device__ __forceinline__ bf16x8 mk8(unsigned int w0, unsigned int w1,
                                      unsigned int w2, unsigned int w3) {
  u32x4 u = {w0, w1, w2, w3};
  return __builtin_bit_cast(bf16x8, u);
}

// V swizzle, 64-byte XOR window (V rows are 320 B).
#define SWZV(d) ((((d) & 7) ^ (((d) >> 4) & 7)) << 3)

// Sliding-window split (r12) + MANUALLY BATCHED staging (r14): issue all 20
// f32x4 global loads into named regs first, then convert+write to LDS. The
// compiler's natural schedule sinks each load next to its LDS write -> ~10
// serial HBM round-trips per wave (~7k cyc, 60% of the block critical chain,
// r13: VGPR stayed 52). The two-phase structure pipelines them into ~1
// round-trip; first write waits vmcnt(19) so writes trickle in-order.
__global__ __launch_bounds__(512, 4)
void swa_fwd(const float* __restrict__ Qg, const float* __restrict__ Kg,
             const float* __restrict__ Vg, float* __restrict__ Og) {
  __shared__ __align__(16) unsigned char Kl[40960];  // [c:160][d:128] bf16
  __shared__ __align__(16) unsigned char Vl[40960];  // V^T [d:128][c:160] bf16

  // XCD-aware bijective swizzle (nwg = 2048, divisible by 8).
  const int nwg  = gridDim.x;
  const int bid0 = blockIdx.x;
  const int bid  = (bid0 & 7) * (nwg >> 3) + (bid0 >> 3);

  const int j    = bid & 3;           // 32-row sub-block within the q-block
  const int n    = (bid >> 2) & 31;   // q-block index
  const int hkv  = (bid >> 7) & 7;
  const int b    = bid >> 10;
  const int tid  = threadIdx.x;
  const int lane = tid & 63;
  const int wv   = tid >> 6;          // 0..7
  const int g    = lane >> 4;         // 16-lane group 0..3
  const int l15  = lane & 15;

  // 8 units = 4 heads x 2 local 16-row q-chunks; one unit per wave.
  const int cc = wv & 1;              // local chunk 0..1
  const int h  = hkv * 4 + (wv >> 1);
  const int cg = 2 * j + cc;          // global chunk 0..7 (n==0 masking)
  const int qrow = n * QBLK + 32 * j + cc * 16 + l15;

  // ---- Q fragments: independent loads join the staging batch ----
  const float* qp = Qg + (size_t)(b * S_LEN + qrow) * (HQ * DD) + h * DD + g * 8;
  bf16x8 qf[4];
  #pragma unroll
  for (int dc = 0; dc < 4; ++dc) {
    f32x4 a  = *(const f32x4*)(qp + dc * 32);
    f32x4 c4 = *(const f32x4*)(qp + dc * 32 + 4);
    qf[dc] = mk8(pk2(a[0], a[1]), pk2(a[2], a[3]),
                 pk2(c4[0], c4[1]), pk2(c4[2], c4[3]));
  }

  // ---- stage the 160-key window, phase 1: ISSUE all 20 loads ----
  const int kbase = (n - 1) * QBLK + 32 * j;
  const int c0 = tid >> 5;            // per-thread row base 0..15 (c&15 == c0)
  const int dc = tid & 31;            // float4 index within d
  f32x4 xk[10], xv[10];
  #pragma unroll
  for (int i = 0; i < 10; ++i) {
    int tk = kbase + c0 + i * 16;
    tk = tk > 0 ? tk : 0;             // branchless clamp (n==0 left pad)
    const size_t base = (size_t)(b * S_LEN + tk) * KVROW + hkv * DD + dc * 4;
    xk[i] = *(const f32x4*)(Kg + base);
    xv[i] = *(const f32x4*)(Vg + base);
  }
  // ---- phase 2: convert + write (waits trickle in load order) ----
  #pragma unroll
  for (int i = 0; i < 10; ++i) {
    const int c = c0 + i * 16;
    u32x2 kw = { pk2(xk[i][0], xk[i][1]), pk2(xk[i][2], xk[i][3]) };
    *(u32x2*)(&Kl[c * 256 + ((dc * 8) ^ (c0 << 4))]) = kw;
    #pragma unroll
    for (int j4 = 0; j4 < 4; ++j4) {  // transposed scatter for V
      const int d = dc * 4 + j4;
      *(unsigned short*)(&Vl[d * 320 + ((c * 2) ^ SWZV(d))]) =
          __builtin_bit_cast(unsigned short, (__bf16)xv[i][j4]);
    }
  }
  __syncthreads();

  const float SC = 0.08838834764831845f * 1.44269504088896340f; // 1/sqrt(128)*log2e

  // O^T accumulators: o[dt] covers d = dt*16 + g*4 + r, q = l15.
  f32x4 o[8];
  #pragma unroll
  for (int dt = 0; dt < 8; ++dt) o[dt] = (f32x4){0.f, 0.f, 0.f, 0.f};
  float ls = 0.f;

  // 9 16-key tiles (local tiles cc..cc+8 in the 10-tile buffer), in pairs.
  #pragma unroll
  for (int pp = 0; pp < 5; ++pp) {
    const int tt0 = 2 * pp, tt1 = 2 * pp + 1;
    // n==0: window tiles with cg+tt < 8 are fully masked (left pad).
    if (n == 0 && cg + tt1 < 8) continue;   // both tiles dead

    unsigned int w0 = 0, w1 = 0, w2 = 0, w3 = 0;

    // ---- tile tt0: S^T = K_tile * Q^T (4 MFMAs over d) ----
    if (!(n == 0 && cg + tt0 < 8)) {
      const int c = (cc + tt0) * 16 + l15;   // key row (A: row=l15)
      f32x4 acc = {0.f, 0.f, 0.f, 0.f};
      __builtin_amdgcn_s_setprio(1);
      #pragma unroll
      for (int dcc = 0; dcc < 4; ++dcc) {
        const bf16x8 kf = *(const bf16x8*)(
            &Kl[c * 256 + ((dcc * 64 + g * 16) ^ ((c & 15) << 4))]);
        acc = __builtin_amdgcn_mfma_f32_16x16x32_bf16(kf, qf[dcc], acc, 0, 0, 0);
      }
      __builtin_amdgcn_s_setprio(0);
      // mask: tt0==0: g4r>l15 ; tt0==8: g4r<=l15 ; else all valid.
      float p[4];
      #pragma unroll
      for (int r = 0; r < 4; ++r) {
        const int g4r = g * 4 + r;
        const float e = __builtin_amdgcn_exp2f(acc[r] * SC);
        bool valid = true;
        if (pp == 0) valid = (g4r > l15);
        if (pp == 4) valid = (g4r <= l15);
        p[r] = valid ? e : 0.f;
        ls += p[r];
      }
      w0 = pk2(p[0], p[1]);
      w1 = pk2(p[2], p[3]);
    }

    // ---- tile tt1 (pp<4 only; interior tiles never need a mask) ----
    if (pp < 4 && !(n == 0 && cg + tt1 < 8)) {
      const int c = (cc + tt1) * 16 + l15;
      f32x4 acc = {0.f, 0.f, 0.f, 0.f};
      __builtin_amdgcn_s_setprio(1);
      #pragma unroll
      for (int dcc = 0; dcc < 4; ++dcc) {
        const bf16x8 kf = *(const bf16x8*)(
            &Kl[c * 256 + ((dcc * 64 + g * 16) ^ ((c & 15) << 4))]);
        acc = __builtin_amdgcn_mfma_f32_16x16x32_bf16(kf, qf[dcc], acc, 0, 0, 0);
      }
      __builtin_amdgcn_s_setprio(0);
      float p0 = __builtin_amdgcn_exp2f(acc[0] * SC);
      float p1 = __builtin_amdgcn_exp2f(acc[1] * SC);
      float p2 = __builtin_amdgcn_exp2f(acc[2] * SC);
      float p3 = __builtin_amdgcn_exp2f(acc[3] * SC);
      ls += p0 + p1 + p2 + p3;
      w2 = pk2(p0, p1);
      w3 = pk2(p2, p3);
    }

    // ---- PV with co-permuted key order: B = P^T in-register already;
    //      A (V^T) reads keys {tt0: g*4..+3, tt1: g*4..+3} to match. ----
    const bf16x8 pf = mk8(w0, w1, w2, w3);
    const int ck0 = ((cc + tt0) * 16 + g * 4) * 2;              // byte col
    const int ck1 = (pp < 4) ? ((cc + tt1) * 16 + g * 4) * 2 : ck0;
    __builtin_amdgcn_s_setprio(1);
    #pragma unroll
    for (int dt = 0; dt < 8; ++dt) {
      const int d  = dt * 16 + l15;       // A row = l15 within d-tile
      const int rb = d * 320;
      const int sz = SWZV(d);
      const u32x2 a0 = *(const u32x2*)(&Vl[rb + (ck0 ^ sz)]);
      const u32x2 a1 = *(const u32x2*)(&Vl[rb + (ck1 ^ sz)]);
      const bf16x8 vf = mk8(a0[0], a0[1], a1[0], a1[1]);
      o[dt] = __builtin_amdgcn_mfma_f32_16x16x32_bf16(vf, pf, o[dt], 0, 0, 0);
    }
    __builtin_amdgcn_s_setprio(0);
  }

  // ---- softmax denominator: all outputs of this lane share q = l15 ----
  ls += __shfl_xor(ls, 16);
  ls += __shfl_xor(ls, 32);
  const float inv = 1.0f / ls;

  float* op = Og + (size_t)(b * S_LEN + qrow) * (HQ * DD) + h * DD + g * 4;
  #pragma unroll
  for (int dt = 0; dt < 8; ++dt) {
    f32x4 v = o[dt];
    v[0] *= inv; v[1] *= inv; v[2] *= inv; v[3] *= inv;
    *(f32x4*)(op + dt * 16) = v;
  }
}

extern "C" void kernel_launch(void* const* d_in, const int* in_sizes, int n_in,
                              void* d_out, int out_size, void* d_ws, size_t ws_size,
                              hipStream_t stream) {
  const float* Q = (const float*)d_in[0];
  const float* K = (const float*)d_in[1];
  const float* V = (const float*)d_in[2];
  float* O = (float*)d_out;
  const int B = in_sizes[0] / (S_LEN * HQ * DD);
  const int nblocks = B * HKV * (S_LEN / QBLK) * 4;   // b, hkv, n, j (j fastest)
  swa_fwd<<<dim3(nblocks), dim3(512), 0, stream>>>(Q, K, V, O);
}

// Round 15
// 84.995 us; speedup vs baseline: 1.0868x; 1.0263x over previous
//
#include <hip/hip_runtime.h>
#include <stdint.h>

#define S_LEN 4096
#define HQ 32
#define HKV 8
#define DD 128
#define QBLK 128
#define KVROW (HKV * DD)

typedef __attribute__((ext_vector_type(8)))  __bf16 bf16x8;
typedef __attribute__((ext_vector_type(2)))  __bf16 bf16x2;
typedef __attribute__((ext_vector_type(4)))  float  f32x4;
typedef __attribute__((ext_vector_type(2)))  unsigned int u32x2;
typedef __attribute__((ext_vector_type(4)))  unsigned int u32x4;

// RNE f32x2 -> packed bf16x2 (compiler emits v_cvt_pk_bf16_f32).
__device__ __forceinline__ unsigned int pk2(float lo, float hi2) {
  bf16x2 t = {(__bf16)lo, (__bf16)hi2};
  return __builtin_bit_cast(unsigned int, t);
}
__device__ __forceinline__ bf16x8 mk8(unsigned int w0, unsigned int w1,
                                      unsigned int w2, unsigned int w3) {
  u32x4 u = {w0, w1, w2, w3};
  return __builtin_bit_cast(bf16x8, u);
}

// V swizzle, 64-byte XOR window (V rows are 320 B).
#define SWZV(d) ((((d) & 7) ^ (((d) >> 4) & 7)) << 3)

// r15: HALF-WINDOW async staging. r14's 20-load batch needs 80 data VGPRs +
// ~60 base > the 128-reg budget of 4 waves/SIMD -> allocator sank the loads
// (VGPR stayed 60, ~4 serial round-trips). A 10-load half = 40 data VGPRs
// fits. Half 0 (rows 0-79) staged up-front; half 1 (rows 80-159) ISSUED, then
// compute pairs pp=0,1 (tiles 0-4, all in half 0) run while those loads fly;
// writes land after a sched_barrier pin, one more barrier, then pp=2-4.
__global__ __launch_bounds__(512, 4)
void swa_fwd(const float* __restrict__ Qg, const float* __restrict__ Kg,
             const float* __restrict__ Vg, float* __restrict__ Og) {
  __shared__ __align__(16) unsigned char Kl[40960];  // [c:160][d:128] bf16
  __shared__ __align__(16) unsigned char Vl[40960];  // V^T [d:128][c:160] bf16

  // XCD-aware bijective swizzle (nwg = 2048, divisible by 8).
  const int nwg  = gridDim.x;
  const int bid0 = blockIdx.x;
  const int bid  = (bid0 & 7) * (nwg >> 3) + (bid0 >> 3);

  const int j    = bid & 3;           // 32-row sub-block within the q-block
  const int n    = (bid >> 2) & 31;   // q-block index
  const int hkv  = (bid >> 7) & 7;
  const int b    = bid >> 10;
  const int tid  = threadIdx.x;
  const int lane = tid & 63;
  const int wv   = tid >> 6;          // 0..7
  const int g    = lane >> 4;         // 16-lane group 0..3
  const int l15  = lane & 15;

  // 8 units = 4 heads x 2 local 16-row q-chunks; one unit per wave.
  const int cc = wv & 1;              // local chunk 0..1
  const int h  = hkv * 4 + (wv >> 1);
  const int cg = 2 * j + cc;          // global chunk 0..7 (n==0 masking)
  const int qrow = n * QBLK + 32 * j + cc * 16 + l15;

  // ---- Q fragments ----
  const float* qp = Qg + (size_t)(b * S_LEN + qrow) * (HQ * DD) + h * DD + g * 8;
  bf16x8 qf[4];
  #pragma unroll
  for (int dc4 = 0; dc4 < 4; ++dc4) {
    f32x4 a  = *(const f32x4*)(qp + dc4 * 32);
    f32x4 c4 = *(const f32x4*)(qp + dc4 * 32 + 4);
    qf[dc4] = mk8(pk2(a[0], a[1]), pk2(a[2], a[3]),
                  pk2(c4[0], c4[1]), pk2(c4[2], c4[3]));
  }

  const int kbase = (n - 1) * QBLK + 32 * j;
  const int c0 = tid >> 5;            // per-thread row base 0..15
  const int dc = tid & 31;            // float4 index within d
  const size_t kvoff = hkv * DD + dc * 4;

  // ---- half 0: rows 0..79 (5 rows/thread, 10 loads = 40 VGPR in flight) ----
  f32x4 xk0[5], xv0[5];
  #pragma unroll
  for (int i = 0; i < 5; ++i) {
    int tk = kbase + c0 + i * 16;
    tk = tk > 0 ? tk : 0;             // branchless clamp (n==0 left pad)
    const size_t base = (size_t)(b * S_LEN + tk) * KVROW + kvoff;
    xk0[i] = *(const f32x4*)(Kg + base);
    xv0[i] = *(const f32x4*)(Vg + base);
  }
  #pragma unroll
  for (int i = 0; i < 5; ++i) {
    const int c = c0 + i * 16;
    u32x2 kw = { pk2(xk0[i][0], xk0[i][1]), pk2(xk0[i][2], xk0[i][3]) };
    *(u32x2*)(&Kl[c * 256 + ((dc * 8) ^ (c0 << 4))]) = kw;
    #pragma unroll
    for (int j4 = 0; j4 < 4; ++j4) {
      const int d = dc * 4 + j4;
      *(unsigned short*)(&Vl[d * 320 + ((c * 2) ^ SWZV(d))]) =
          __builtin_bit_cast(unsigned short, (__bf16)xv0[i][j4]);
    }
  }
  __syncthreads();

  // ---- half 1: ISSUE loads now; they fly under compute pp=0,1 ----
  f32x4 xk1[5], xv1[5];
  #pragma unroll
  for (int i = 0; i < 5; ++i) {
    int tk = kbase + c0 + (i + 5) * 16;
    tk = tk > 0 ? tk : 0;
    const size_t base = (size_t)(b * S_LEN + tk) * KVROW + kvoff;
    xk1[i] = *(const f32x4*)(Kg + base);
    xv1[i] = *(const f32x4*)(Vg + base);
  }

  const float SC = 0.08838834764831845f * 1.44269504088896340f; // 1/sqrt(128)*log2e

  // O^T accumulators: o[dt] covers d = dt*16 + g*4 + r, q = l15.
  f32x4 o[8];
  #pragma unroll
  for (int dt = 0; dt < 8; ++dt) o[dt] = (f32x4){0.f, 0.f, 0.f, 0.f};
  float ls = 0.f;

  // ---- compute pairs: macro'd body so we can split the pp range ----
#define PAIR_BODY(pp)                                                         \
  {                                                                           \
    const int tt0 = 2 * (pp), tt1 = 2 * (pp) + 1;                             \
    if (!(n == 0 && cg + tt1 < 8)) {                                          \
      unsigned int w0 = 0, w1 = 0, w2 = 0, w3 = 0;                            \
      if (!(n == 0 && cg + tt0 < 8)) {                                        \
        const int c = (cc + tt0) * 16 + l15;                                  \
        f32x4 acc = {0.f, 0.f, 0.f, 0.f};                                     \
        __builtin_amdgcn_s_setprio(1);                                        \
        _Pragma("unroll")                                                     \
        for (int dcc = 0; dcc < 4; ++dcc) {                                   \
          const bf16x8 kf = *(const bf16x8*)(                                 \
              &Kl[c * 256 + ((dcc * 64 + g * 16) ^ ((c & 15) << 4))]);        \
          acc = __builtin_amdgcn_mfma_f32_16x16x32_bf16(kf, qf[dcc], acc,     \
                                                        0, 0, 0);             \
        }                                                                     \
        __builtin_amdgcn_s_setprio(0);                                        \
        float p[4];                                                           \
        _Pragma("unroll")                                                     \
        for (int r = 0; r < 4; ++r) {                                         \
          const int g4r = g * 4 + r;                                          \
          const float e = __builtin_amdgcn_exp2f(acc[r] * SC);                \
          bool valid = true;                                                  \
          if ((pp) == 0) valid = (g4r > l15);                                 \
          if ((pp) == 4) valid = (g4r <= l15);                                \
          p[r] = valid ? e : 0.f;                                             \
          ls += p[r];                                                         \
        }                                                                     \
        w0 = pk2(p[0], p[1]);                                                 \
        w1 = pk2(p[2], p[3]);                                                 \
      }                                                                       \
      if ((pp) < 4 && !(n == 0 && cg + tt1 < 8)) {                            \
        const int c = (cc + tt1) * 16 + l15;                                  \
        f32x4 acc = {0.f, 0.f, 0.f, 0.f};                                     \
        __builtin_amdgcn_s_setprio(1);                                        \
        _Pragma("unroll")                                                     \
        for (int dcc = 0; dcc < 4; ++dcc) {                                   \
          const bf16x8 kf = *(const bf16x8*)(                                 \
              &Kl[c * 256 + ((dcc * 64 + g * 16) ^ ((c & 15) << 4))]);        \
          acc = __builtin_amdgcn_mfma_f32_16x16x32_bf16(kf, qf[dcc], acc,     \
                                                        0, 0, 0);             \
        }                                                                     \
        __builtin_amdgcn_s_setprio(0);                                        \
        float p0 = __builtin_amdgcn_exp2f(acc[0] * SC);                       \
        float p1 = __builtin_amdgcn_exp2f(acc[1] * SC);                       \
        float p2 = __builtin_amdgcn_exp2f(acc[2] * SC);                       \
        float p3 = __builtin_amdgcn_exp2f(acc[3] * SC);                       \
        ls += p0 + p1 + p2 + p3;                                              \
        w2 = pk2(p0, p1);                                                     \
        w3 = pk2(p2, p3);                                                     \
      }                                                                       \
      const bf16x8 pf = mk8(w0, w1, w2, w3);                                  \
      const int ck0 = ((cc + tt0) * 16 + g * 4) * 2;                          \
      const int ck1 = ((pp) < 4) ? ((cc + tt1) * 16 + g * 4) * 2 : ck0;       \
      __builtin_amdgcn_s_setprio(1);                                          \
      _Pragma("unroll")                                                       \
      for (int dt = 0; dt < 8; ++dt) {                                        \
        const int d  = dt * 16 + l15;                                         \
        const int rb = d * 320;                                               \
        const int sz = SWZV(d);                                               \
        const u32x2 a0 = *(const u32x2*)(&Vl[rb + (ck0 ^ sz)]);               \
        const u32x2 a1 = *(const u32x2*)(&Vl[rb + (ck1 ^ sz)]);               \
        const bf16x8 vf = mk8(a0[0], a0[1], a1[0], a1[1]);                    \
        o[dt] = __builtin_amdgcn_mfma_f32_16x16x32_bf16(vf, pf, o[dt],        \
                                                        0, 0, 0);             \
      }                                                                       \
      __builtin_amdgcn_s_setprio(0);                                          \
    }                                                                         \
  }

  // pairs 0,1 use tiles cc..cc+3 (keys < 80): half 0 only.
  PAIR_BODY(0)
  PAIR_BODY(1)

  // ---- pin: don't hoist half-1 LDS writes (and their vmcnt waits) above
  // the overlapped compute ----
  __builtin_amdgcn_sched_barrier(0);
  #pragma unroll
  for (int i = 0; i < 5; ++i) {
    const int c = c0 + (i + 5) * 16;
    u32x2 kw = { pk2(xk1[i][0], xk1[i][1]), pk2(xk1[i][2], xk1[i][3]) };
    *(u32x2*)(&Kl[c * 256 + ((dc * 8) ^ (c0 << 4))]) = kw;
    #pragma unroll
    for (int j4 = 0; j4 < 4; ++j4) {
      const int d = dc * 4 + j4;
      *(unsigned short*)(&Vl[d * 320 + ((c * 2) ^ SWZV(d))]) =
          __builtin_bit_cast(unsigned short, (__bf16)xv1[i][j4]);
    }
  }
  __syncthreads();

  // pairs 2..4 use tiles up to cc+8 (keys < 160): need half 1.
  PAIR_BODY(2)
  PAIR_BODY(3)
  PAIR_BODY(4)
#undef PAIR_BODY

  // ---- softmax denominator: all outputs of this lane share q = l15 ----
  ls += __shfl_xor(ls, 16);
  ls += __shfl_xor(ls, 32);
  const float inv = 1.0f / ls;

  float* op = Og + (size_t)(b * S_LEN + qrow) * (HQ * DD) + h * DD + g * 4;
  #pragma unroll
  for (int dt = 0; dt < 8; ++dt) {
    f32x4 v = o[dt];
    v[0] *= inv; v[1] *= inv; v[2] *= inv; v[3] *= inv;
    *(f32x4*)(op + dt * 16) = v;
  }
}

extern "C" void kernel_launch(void* const* d_in, const int* in_sizes, int n_in,
                              void* d_out, int out_size, void* d_ws, size_t ws_size,
                              hipStream_t stream) {
  const float* Q = (const float*)d_in[0];
  const float* K = (const float*)d_in[1];
  const float* V = (const float*)d_in[2];
  float* O = (float*)d_out;
  const int B = in_sizes[0] / (S_LEN * HQ * DD);
  const int nblocks = B * HKV * (S_LEN / QBLK) * 4;   // b, hkv, n, j (j fastest)
  swa_fwd<<<dim3(nblocks), dim3(512), 0, stream>>>(Q, K, V, O);
}

// Round 16
// 82.842 us; speedup vs baseline: 1.1151x; 1.0260x over previous
//
#include <hip/hip_runtime.h>
#include <stdint.h>

#define S_LEN 4096
#define HQ 32
#define HKV 8
#define DD 128
#define QBLK 128
#define KVROW (HKV * DD)

typedef __attribute__((ext_vector_type(8)))  __bf16 bf16x8;
typedef __attribute__((ext_vector_type(2)))  __bf16 bf16x2;
typedef __attribute__((ext_vector_type(4)))  float  f32x4;
typedef __attribute__((ext_vector_type(2)))  unsigned int u32x2;
typedef __attribute__((ext_vector_type(4)))  unsigned int u32x4;

// RNE f32x2 -> packed bf16x2 (compiler emits v_cvt_pk_bf16_f32).
__device__ __forceinline__ unsigned int pk2(float lo, float hi2) {
  bf16x2 t = {(__bf16)lo, (__bf16)hi2};
  return __builtin_bit_cast(unsigned int, t);
}
__device__ __forceinline__ bf16x8 mk8(unsigned int w0, unsigned int w1,
                                      unsigned int w2, unsigned int w3) {
  u32x4 u = {w0, w1, w2, w3};
  return __builtin_bit_cast(bf16x8, u);
}

// V swizzle, 64-byte XOR window (V rows are 320 B; (c*2)|56 <= 318 < 320 so
// the XOR never escapes the row).
#define SWZV(d) ((((d) & 7) ^ (((d) >> 4) & 7)) << 3)

// r16: r15's half-window async staging with the scheduling fence placed
// CORRECTLY. r15 put sched_barrier(0) only before the half-1 WRITE loop, so
// the scheduler sank the half-1 LOADS down to that fence (after compute) --
// zero overlap, VGPR stayed 64. The fence must sit immediately AFTER the
// load-issue loop: loads cannot sink past it, their 40 dest VGPRs stay live
// across PAIR_BODY(0,1), and the L2/L3 round-trip hides under the MFMA+exp
// of pairs 0-1. Peak live ~115 unified regs (o[8] -> AGPR) <= 128 budget.
__global__ __launch_bounds__(512, 4)
void swa_fwd(const float* __restrict__ Qg, const float* __restrict__ Kg,
             const float* __restrict__ Vg, float* __restrict__ Og) {
  __shared__ __align__(16) unsigned char Kl[40960];  // [c:160][d:128] bf16
  __shared__ __align__(16) unsigned char Vl[40960];  // V^T [d:128][c:160] bf16

  // XCD-aware bijective swizzle (nwg = 2048, divisible by 8).
  const int nwg  = gridDim.x;
  const int bid0 = blockIdx.x;
  const int bid  = (bid0 & 7) * (nwg >> 3) + (bid0 >> 3);

  const int j    = bid & 3;           // 32-row sub-block within the q-block
  const int n    = (bid >> 2) & 31;   // q-block index
  const int hkv  = (bid >> 7) & 7;
  const int b    = bid >> 10;
  const int tid  = threadIdx.x;
  const int lane = tid & 63;
  const int wv   = tid >> 6;          // 0..7
  const int g    = lane >> 4;         // 16-lane group 0..3
  const int l15  = lane & 15;

  // 8 units = 4 heads x 2 local 16-row q-chunks; one unit per wave.
  const int cc = wv & 1;              // local chunk 0..1
  const int h  = hkv * 4 + (wv >> 1);
  const int cg = 2 * j + cc;          // global chunk 0..7 (n==0 masking)
  const int qrow = n * QBLK + 32 * j + cc * 16 + l15;

  // ---- Q fragments ----
  const float* qp = Qg + (size_t)(b * S_LEN + qrow) * (HQ * DD) + h * DD + g * 8;
  bf16x8 qf[4];
  #pragma unroll
  for (int dc4 = 0; dc4 < 4; ++dc4) {
    f32x4 a  = *(const f32x4*)(qp + dc4 * 32);
    f32x4 c4 = *(const f32x4*)(qp + dc4 * 32 + 4);
    qf[dc4] = mk8(pk2(a[0], a[1]), pk2(a[2], a[3]),
                  pk2(c4[0], c4[1]), pk2(c4[2], c4[3]));
  }

  const int kbase = (n - 1) * QBLK + 32 * j;
  const int c0 = tid >> 5;            // per-thread row base 0..15
  const int dc = tid & 31;            // float4 index within d
  const size_t kvoff = hkv * DD + dc * 4;

  // ---- half 0: rows 0..79 (5 rows/thread, 10 loads = 40 VGPR in flight) ----
  f32x4 xk0[5], xv0[5];
  #pragma unroll
  for (int i = 0; i < 5; ++i) {
    int tk = kbase + c0 + i * 16;
    tk = tk > 0 ? tk : 0;             // branchless clamp (n==0 left pad)
    const size_t base = (size_t)(b * S_LEN + tk) * KVROW + kvoff;
    xk0[i] = *(const f32x4*)(Kg + base);
    xv0[i] = *(const f32x4*)(Vg + base);
  }
  #pragma unroll
  for (int i = 0; i < 5; ++i) {
    const int c = c0 + i * 16;
    u32x2 kw = { pk2(xk0[i][0], xk0[i][1]), pk2(xk0[i][2], xk0[i][3]) };
    *(u32x2*)(&Kl[c * 256 + ((dc * 8) ^ (c0 << 4))]) = kw;
    #pragma unroll
    for (int j4 = 0; j4 < 4; ++j4) {
      const int d = dc * 4 + j4;
      *(unsigned short*)(&Vl[d * 320 + ((c * 2) ^ SWZV(d))]) =
          __builtin_bit_cast(unsigned short, (__bf16)xv0[i][j4]);
    }
  }
  __syncthreads();

  // ---- half 1: ISSUE loads; HARD FENCE pins them above the compute ----
  f32x4 xk1[5], xv1[5];
  #pragma unroll
  for (int i = 0; i < 5; ++i) {
    int tk = kbase + c0 + (i + 5) * 16;
    tk = tk > 0 ? tk : 0;
    const size_t base = (size_t)(b * S_LEN + tk) * KVROW + kvoff;
    xk1[i] = *(const f32x4*)(Kg + base);
    xv1[i] = *(const f32x4*)(Vg + base);
  }
  __builtin_amdgcn_sched_barrier(0);   // loads may NOT sink past this point

  const float SC = 0.08838834764831845f * 1.44269504088896340f; // 1/sqrt(128)*log2e

  // O^T accumulators: o[dt] covers d = dt*16 + g*4 + r, q = l15.
  f32x4 o[8];
  #pragma unroll
  for (int dt = 0; dt < 8; ++dt) o[dt] = (f32x4){0.f, 0.f, 0.f, 0.f};
  float ls = 0.f;

  // ---- compute pairs: macro'd body so we can split the pp range ----
#define PAIR_BODY(pp)                                                         \
  {                                                                           \
    const int tt0 = 2 * (pp), tt1 = 2 * (pp) + 1;                             \
    if (!(n == 0 && cg + tt1 < 8)) {                                          \
      unsigned int w0 = 0, w1 = 0, w2 = 0, w3 = 0;                            \
      if (!(n == 0 && cg + tt0 < 8)) {                                        \
        const int c = (cc + tt0) * 16 + l15;                                  \
        f32x4 acc = {0.f, 0.f, 0.f, 0.f};                                     \
        __builtin_amdgcn_s_setprio(1);                                        \
        _Pragma("unroll")                                                     \
        for (int dcc = 0; dcc < 4; ++dcc) {                                   \
          const bf16x8 kf = *(const bf16x8*)(                                 \
              &Kl[c * 256 + ((dcc * 64 + g * 16) ^ ((c & 15) << 4))]);        \
          acc = __builtin_amdgcn_mfma_f32_16x16x32_bf16(kf, qf[dcc], acc,     \
                                                        0, 0, 0);             \
        }                                                                     \
        __builtin_amdgcn_s_setprio(0);                                        \
        float p[4];                                                           \
        _Pragma("unroll")                                                     \
        for (int r = 0; r < 4; ++r) {                                         \
          const int g4r = g * 4 + r;                                          \
          const float e = __builtin_amdgcn_exp2f(acc[r] * SC);                \
          bool valid = true;                                                  \
          if ((pp) == 0) valid = (g4r > l15);                                 \
          if ((pp) == 4) valid = (g4r <= l15);                                \
          p[r] = valid ? e : 0.f;                                             \
          ls += p[r];                                                         \
        }                                                                     \
        w0 = pk2(p[0], p[1]);                                                 \
        w1 = pk2(p[2], p[3]);                                                 \
      }                                                                       \
      if ((pp) < 4 && !(n == 0 && cg + tt1 < 8)) {                            \
        const int c = (cc + tt1) * 16 + l15;                                  \
        f32x4 acc = {0.f, 0.f, 0.f, 0.f};                                     \
        __builtin_amdgcn_s_setprio(1);                                        \
        _Pragma("unroll")                                                     \
        for (int dcc = 0; dcc < 4; ++dcc) {                                   \
          const bf16x8 kf = *(const bf16x8*)(                                 \
              &Kl[c * 256 + ((dcc * 64 + g * 16) ^ ((c & 15) << 4))]);        \
          acc = __builtin_amdgcn_mfma_f32_16x16x32_bf16(kf, qf[dcc], acc,     \
                                                        0, 0, 0);             \
        }                                                                     \
        __builtin_amdgcn_s_setprio(0);                                        \
        float p0 = __builtin_amdgcn_exp2f(acc[0] * SC);                       \
        float p1 = __builtin_amdgcn_exp2f(acc[1] * SC);                       \
        float p2 = __builtin_amdgcn_exp2f(acc[2] * SC);                       \
        float p3 = __builtin_amdgcn_exp2f(acc[3] * SC);                       \
        ls += p0 + p1 + p2 + p3;                                              \
        w2 = pk2(p0, p1);                                                     \
        w3 = pk2(p2, p3);                                                     \
      }                                                                       \
      const bf16x8 pf = mk8(w0, w1, w2, w3);                                  \
      const int ck0 = ((cc + tt0) * 16 + g * 4) * 2;                          \
      const int ck1 = ((pp) < 4) ? ((cc + tt1) * 16 + g * 4) * 2 : ck0;       \
      __builtin_amdgcn_s_setprio(1);                                          \
      _Pragma("unroll")                                                       \
      for (int dt = 0; dt < 8; ++dt) {                                        \
        const int d  = dt * 16 + l15;                                         \
        const int rb = d * 320;                                               \
        const int sz = SWZV(d);                                               \
        const u32x2 a0 = *(const u32x2*)(&Vl[rb + (ck0 ^ sz)]);               \
        const u32x2 a1 = *(const u32x2*)(&Vl[rb + (ck1 ^ sz)]);               \
        const bf16x8 vf = mk8(a0[0], a0[1], a1[0], a1[1]);                    \
        o[dt] = __builtin_amdgcn_mfma_f32_16x16x32_bf16(vf, pf, o[dt],        \
                                                        0, 0, 0);             \
      }                                                                       \
      __builtin_amdgcn_s_setprio(0);                                          \
    }                                                                         \
  }

  // pairs 0,1 use tiles cc..cc+3 (keys < 80): half 0 only.
  PAIR_BODY(0)
  PAIR_BODY(1)

  // ---- half-1 writes land here (loads completed during pairs 0-1) ----
  __builtin_amdgcn_sched_barrier(0);
  #pragma unroll
  for (int i = 0; i < 5; ++i) {
    const int c = c0 + (i + 5) * 16;
    u32x2 kw = { pk2(xk1[i][0], xk1[i][1]), pk2(xk1[i][2], xk1[i][3]) };
    *(u32x2*)(&Kl[c * 256 + ((dc * 8) ^ (c0 << 4))]) = kw;
    #pragma unroll
    for (int j4 = 0; j4 < 4; ++j4) {
      const int d = dc * 4 + j4;
      *(unsigned short*)(&Vl[d * 320 + ((c * 2) ^ SWZV(d))]) =
          __builtin_bit_cast(unsigned short, (__bf16)xv1[i][j4]);
    }
  }
  __syncthreads();

  // pairs 2..4 use tiles up to cc+8 (keys < 160): need half 1.
  PAIR_BODY(2)
  PAIR_BODY(3)
  PAIR_BODY(4)
#undef PAIR_BODY

  // ---- softmax denominator: all outputs of this lane share q = l15 ----
  ls += __shfl_xor(ls, 16);
  ls += __shfl_xor(ls, 32);
  const float inv = 1.0f / ls;

  float* op = Og + (size_t)(b * S_LEN + qrow) * (HQ * DD) + h * DD + g * 4;
  #pragma unroll
  for (int dt = 0; dt < 8; ++dt) {
    f32x4 v = o[dt];
    v[0] *= inv; v[1] *= inv; v[2] *= inv; v[3] *= inv;
    *(f32x4*)(op + dt * 16) = v;
  }
}

extern "C" void kernel_launch(void* const* d_in, const int* in_sizes, int n_in,
                              void* d_out, int out_size, void* d_ws, size_t ws_size,
                              hipStream_t stream) {
  const float* Q = (const float*)d_in[0];
  const float* K = (const float*)d_in[1];
  const float* V = (const float*)d_in[2];
  float* O = (float*)d_out;
  const int B = in_sizes[0] / (S_LEN * HQ * DD);
  const int nblocks = B * HKV * (S_LEN / QBLK) * 4;   // b, hkv, n, j (j fastest)
  swa_fwd<<<dim3(nblocks), dim3(512), 0, stream>>>(Q, K, V, O);
}

// Round 17
// 81.078 us; speedup vs baseline: 1.1393x; 1.0218x over previous
//
#include <hip/hip_runtime.h>
#include <stdint.h>

#define S_LEN 4096
#define HQ 32
#define HKV 8
#define DD 128
#define QBLK 128
#define KVROW (HKV * DD)

typedef __attribute__((ext_vector_type(8)))  __bf16 bf16x8;
typedef __attribute__((ext_vector_type(2)))  __bf16 bf16x2;
typedef __attribute__((ext_vector_type(4)))  float  f32x4;
typedef __attribute__((ext_vector_type(2)))  unsigned int u32x2;
typedef __attribute__((ext_vector_type(4)))  unsigned int u32x4;

// RNE f32x2 -> packed bf16x2 (compiler emits v_cvt_pk_bf16_f32).
__device__ __forceinline__ unsigned int pk2(float lo, float hi2) {
  bf16x2 t = {(__bf16)lo, (__bf16)hi2};
  return __builtin_bit_cast(unsigned int, t);
}
__device__ __forceinline__ bf16x8 mk8(unsigned int w0, unsigned int w1,
                                      unsigned int w2, unsigned int w3) {
  u32x4 u = {w0, w1, w2, w3};
  return __builtin_bit_cast(bf16x8, u);
}

// V swizzle, 64-byte XOR window (V rows are 320 B; (c*2)|56 <= 318 < 320).
#define SWZV(d) ((((d) & 7) ^ (((d) >> 4) & 7)) << 3)

// r17: RING-BUFFER WINDOW. One block per (b,hkv,n) processes all four 32-row
// q-sub-blocks, sliding a 160-key K/V ring (mod 10 tiles) by 32 keys per
// phase. vs r12-16 (one block per sub-block): staging traffic / 2.5 (each
// block stages 160 + 3x32 = 256 rows instead of 4x160), grid 2048 -> 512 =
// ONE resident round (2 blocks/CU), and the incremental stage is only 4
// loads/thread (16 regs) -- small enough to stay in flight across the
// compute phase without the allocator sinking it (the r14-16 failure mode).
__global__ __launch_bounds__(512, 4)
void swa_fwd(const float* __restrict__ Qg, const float* __restrict__ Kg,
             const float* __restrict__ Vg, float* __restrict__ Og) {
  __shared__ __align__(16) unsigned char Kl[40960];  // ring [c:160][d:128] bf16
  __shared__ __align__(16) unsigned char Vl[40960];  // ring V^T [d:128][c:160]

  // XCD-aware bijective swizzle (nwg = 512, divisible by 8): adjacent n
  // windows overlap 128 keys -> same-XCD L2 hits.
  const int nwg  = gridDim.x;
  const int bid0 = blockIdx.x;
  const int bid  = (bid0 & 7) * (nwg >> 3) + (bid0 >> 3);

  const int n    = bid & 31;          // q-block index
  const int hkv  = (bid >> 5) & 7;
  const int b    = bid >> 8;
  const int tid  = threadIdx.x;
  const int lane = tid & 63;
  const int wv   = tid >> 6;          // 0..7
  const int g    = lane >> 4;         // 16-lane group 0..3
  const int l15  = lane & 15;

  // 8 waves = 4 heads x 2 16-row chunks; each wave does one unit per phase.
  const int cc = wv & 1;
  const int h  = hkv * 4 + (wv >> 1);

  const int c0 = tid >> 5;            // staging row base 0..15
  const int dc = tid & 31;            // float4 index within d
  const size_t kvoff = hkv * DD + dc * 4;
  const int kbase0 = (n - 1) * QBLK;

  // ---- initial fill: ring rows 0..159 = keys kbase0..kbase0+159 ----
  #pragma unroll
  for (int i = 0; i < 10; ++i) {
    const int c = c0 + i * 16;
    int tk = kbase0 + c;
    tk = tk > 0 ? tk : 0;             // branchless clamp (n==0 left pad;
                                      // garbage rows land in masked-dead tiles)
    const size_t base = (size_t)(b * S_LEN + tk) * KVROW + kvoff;
    const f32x4 xk = *(const f32x4*)(Kg + base);
    const f32x4 xv = *(const f32x4*)(Vg + base);
    u32x2 kw = { pk2(xk[0], xk[1]), pk2(xk[2], xk[3]) };
    *(u32x2*)(&Kl[c * 256 + ((dc * 8) ^ (c0 << 4))]) = kw;
    #pragma unroll
    for (int j4 = 0; j4 < 4; ++j4) {
      const int d = dc * 4 + j4;
      *(unsigned short*)(&Vl[d * 320 + ((c * 2) ^ SWZV(d))]) =
          __builtin_bit_cast(unsigned short, (__bf16)xv[j4]);
    }
  }
  __syncthreads();

  const float SC = 0.08838834764831845f * 1.44269504088896340f; // 1/sqrt(128)*log2e

  #pragma unroll 1
  for (int j = 0; j < 4; ++j) {
    // ---- issue this phase's Q loads ----
    const int qrow = n * QBLK + 32 * j + cc * 16 + l15;
    const float* qp = Qg + (size_t)(b * S_LEN + qrow) * (HQ * DD) + h * DD + g * 8;
    f32x4 qa[4], qb[4];
    #pragma unroll
    for (int d4 = 0; d4 < 4; ++d4) {
      qa[d4] = *(const f32x4*)(qp + d4 * 32);
      qb[d4] = *(const f32x4*)(qp + d4 * 32 + 4);
    }

    // ---- issue the +32-key incremental loads (fly under this compute) ----
    // keys kbase0+160+32j+rr >= 32 always (even n==0) -> no clamp needed.
    f32x4 ik[2], iv[2];
    if (j < 3) {
      #pragma unroll
      for (int ii = 0; ii < 2; ++ii) {
        const int tk = kbase0 + 160 + 32 * j + c0 + 16 * ii;
        const size_t base = (size_t)(b * S_LEN + tk) * KVROW + kvoff;
        ik[ii] = *(const f32x4*)(Kg + base);
        iv[ii] = *(const f32x4*)(Vg + base);
      }
    }

    // ---- convert Q ----
    bf16x8 qf[4];
    #pragma unroll
    for (int d4 = 0; d4 < 4; ++d4)
      qf[d4] = mk8(pk2(qa[d4][0], qa[d4][1]), pk2(qa[d4][2], qa[d4][3]),
                   pk2(qb[d4][0], qb[d4][1]), pk2(qb[d4][2], qb[d4][3]));

    f32x4 o[8];
    #pragma unroll
    for (int dt = 0; dt < 8; ++dt) o[dt] = (f32x4){0.f, 0.f, 0.f, 0.f};
    float ls = 0.f;

    const int bt = 2 * j + cc;        // global tile base (= ring base pre-mod)

#define PAIR_BODY(pp)                                                         \
    {                                                                         \
      const int tt0 = 2 * (pp), tt1 = 2 * (pp) + 1;                           \
      if (!(n == 0 && bt + tt1 < 8)) {                                        \
        unsigned int w0 = 0, w1 = 0, w2 = 0, w3 = 0;                          \
        int rt0 = bt + tt0; rt0 = (rt0 >= 10) ? rt0 - 10 : rt0;               \
        int rt1 = bt + tt1; rt1 = (rt1 >= 10) ? rt1 - 10 : rt1;               \
        if (!(n == 0 && bt + tt0 < 8)) {                                      \
          const int c = rt0 * 16 + l15;                                       \
          f32x4 acc = {0.f, 0.f, 0.f, 0.f};                                   \
          __builtin_amdgcn_s_setprio(1);                                      \
          _Pragma("unroll")                                                   \
          for (int dcc = 0; dcc < 4; ++dcc) {                                 \
            const bf16x8 kf = *(const bf16x8*)(                               \
                &Kl[c * 256 + ((dcc * 64 + g * 16) ^ (l15 << 4))]);           \
            acc = __builtin_amdgcn_mfma_f32_16x16x32_bf16(kf, qf[dcc], acc,   \
                                                          0, 0, 0);           \
          }                                                                   \
          __builtin_amdgcn_s_setprio(0);                                      \
          float p[4];                                                         \
          _Pragma("unroll")                                                   \
          for (int r = 0; r < 4; ++r) {                                       \
            const int g4r = g * 4 + r;                                        \
            const float e = __builtin_amdgcn_exp2f(acc[r] * SC);              \
            bool valid = true;                                                \
            if ((pp) == 0) valid = (g4r > l15);                               \
            if ((pp) == 4) valid = (g4r <= l15);                              \
            p[r] = valid ? e : 0.f;                                           \
            ls += p[r];                                                       \
          }                                                                   \
          w0 = pk2(p[0], p[1]);                                               \
          w1 = pk2(p[2], p[3]);                                               \
        }                                                                     \
        if ((pp) < 4 && !(n == 0 && bt + tt1 < 8)) {                          \
          const int c = rt1 * 16 + l15;                                       \
          f32x4 acc = {0.f, 0.f, 0.f, 0.f};                                   \
          __builtin_amdgcn_s_setprio(1);                                      \
          _Pragma("unroll")                                                   \
          for (int dcc = 0; dcc < 4; ++dcc) {                                 \
            const bf16x8 kf = *(const bf16x8*)(                               \
                &Kl[c * 256 + ((dcc * 64 + g * 16) ^ (l15 << 4))]);           \
            acc = __builtin_amdgcn_mfma_f32_16x16x32_bf16(kf, qf[dcc], acc,   \
                                                          0, 0, 0);           \
          }                                                                   \
          __builtin_amdgcn_s_setprio(0);                                      \
          float p0 = __builtin_amdgcn_exp2f(acc[0] * SC);                     \
          float p1 = __builtin_amdgcn_exp2f(acc[1] * SC);                     \
          float p2 = __builtin_amdgcn_exp2f(acc[2] * SC);                     \
          float p3 = __builtin_amdgcn_exp2f(acc[3] * SC);                     \
          ls += p0 + p1 + p2 + p3;                                            \
          w2 = pk2(p0, p1);                                                   \
          w3 = pk2(p2, p3);                                                   \
        }                                                                     \
        const bf16x8 pf = mk8(w0, w1, w2, w3);                                \
        const int ck0 = (rt0 * 16 + g * 4) * 2;                               \
        const int ck1 = ((pp) < 4) ? (rt1 * 16 + g * 4) * 2 : ck0;            \
        __builtin_amdgcn_s_setprio(1);                                        \
        _Pragma("unroll")                                                     \
        for (int dt = 0; dt < 8; ++dt) {                                      \
          const int d  = dt * 16 + l15;                                       \
          const int rb = d * 320;                                             \
          const int sz = SWZV(d);                                             \
          const u32x2 a0 = *(const u32x2*)(&Vl[rb + (ck0 ^ sz)]);             \
          const u32x2 a1 = *(const u32x2*)(&Vl[rb + (ck1 ^ sz)]);             \
          const bf16x8 vf = mk8(a0[0], a0[1], a1[0], a1[1]);                  \
          o[dt] = __builtin_amdgcn_mfma_f32_16x16x32_bf16(vf, pf, o[dt],      \
                                                          0, 0, 0);           \
        }                                                                     \
        __builtin_amdgcn_s_setprio(0);                                        \
      }                                                                       \
    }

    PAIR_BODY(0)
    PAIR_BODY(1)
    PAIR_BODY(2)
    PAIR_BODY(3)
    PAIR_BODY(4)
#undef PAIR_BODY

    // ---- softmax denominator + store (all outputs of this lane share q) ----
    ls += __shfl_xor(ls, 16);
    ls += __shfl_xor(ls, 32);
    const float inv = 1.0f / ls;

    float* op = Og + (size_t)(b * S_LEN + qrow) * (HQ * DD) + h * DD + g * 4;
    #pragma unroll
    for (int dt = 0; dt < 8; ++dt) {
      f32x4 v = o[dt];
      v[0] *= inv; v[1] *= inv; v[2] *= inv; v[3] *= inv;
      *(f32x4*)(op + dt * 16) = v;
    }

    // ---- slide the ring: overwrite tiles 2j,2j+1 with keys +160..+191 ----
    if (j < 3) {
      __syncthreads();                // all reads of the old tiles done
      #pragma unroll
      for (int ii = 0; ii < 2; ++ii) {
        const int r = 32 * j + c0 + 16 * ii;       // ring row (r & 15 == c0)
        u32x2 kw = { pk2(ik[ii][0], ik[ii][1]), pk2(ik[ii][2], ik[ii][3]) };
        *(u32x2*)(&Kl[r * 256 + ((dc * 8) ^ (c0 << 4))]) = kw;
        #pragma unroll
        for (int j4 = 0; j4 < 4; ++j4) {
          const int d = dc * 4 + j4;
          *(unsigned short*)(&Vl[d * 320 + ((r * 2) ^ SWZV(d))]) =
              __builtin_bit_cast(unsigned short, (__bf16)iv[ii][j4]);
        }
      }
      __syncthreads();                // new tiles visible to all waves
    }
  }
}

extern "C" void kernel_launch(void* const* d_in, const int* in_sizes, int n_in,
                              void* d_out, int out_size, void* d_ws, size_t ws_size,
                              hipStream_t stream) {
  const float* Q = (const float*)d_in[0];
  const float* K = (const float*)d_in[1];
  const float* V = (const float*)d_in[2];
  float* O = (float*)d_out;
  const int B = in_sizes[0] / (S_LEN * HQ * DD);
  const int nblocks = B * HKV * (S_LEN / QBLK);   // b, hkv, n
  swa_fwd<<<dim3(nblocks), dim3(512), 0, stream>>>(Q, K, V, O);
}